// Round 1
// baseline (1747.232 us; speedup 1.0000x reference)
//
#include <hip/hip_runtime.h>

#define NN   16000
#define NE   64000
#define DIN  256
#define HD   64
#define DOUT 256
#define DE   128
#define KHD  32
#define BN_EPS 1e-5f

// ---------------- kernel A: msgn[n] = relu(bn_msg(relu(bn_in(x[n])) @ w1 + b1)) ----------
__global__ __launch_bounds__(256) void k_msgn(
    const float* __restrict__ x, const float* __restrict__ w1, const float* __restrict__ b1,
    const float* __restrict__ g_in, const float* __restrict__ be_in,
    const float* __restrict__ m_in, const float* __restrict__ v_in,
    const float* __restrict__ g_m, const float* __restrict__ be_m,
    const float* __restrict__ m_m, const float* __restrict__ v_m,
    float* __restrict__ msgn)
{
    __shared__ __align__(16) float w1s[DIN * HD];     // 64 KB, [k][j]
    __shared__ __align__(16) float ln[16][DIN];       // 16 KB
    __shared__ float sc_in[DIN], sh_in[DIN], sc_m[HD], sh_m[HD];
    const int t = threadIdx.x;
    const int n0 = blockIdx.x * 16;
    {
        float s = g_in[t] * rsqrtf(v_in[t] + BN_EPS);
        sc_in[t] = s; sh_in[t] = be_in[t] - m_in[t] * s;
        if (t < HD) {
            float s2 = g_m[t] * rsqrtf(v_m[t] + BN_EPS);
            sc_m[t] = s2; sh_m[t] = be_m[t] - m_m[t] * s2;
        }
    }
    for (int i = t; i < DIN * HD; i += 256) w1s[i] = w1[i];
    __syncthreads();
    for (int i = t; i < 16 * DIN; i += 256) {
        int r = i >> 8, c = i & 255;
        float v = x[(size_t)(n0 + r) * DIN + c];
        ln[r][c] = fmaxf(fmaf(v, sc_in[c], sh_in[c]), 0.f);
    }
    __syncthreads();
    const int j = t & 63, nl = t >> 6;   // nl in 0..3
    float a0 = b1[j], a1 = a0, a2 = a0, a3 = a0;
    const float4* ln4_0 = (const float4*)ln[nl];
    const float4* ln4_1 = (const float4*)ln[nl + 4];
    const float4* ln4_2 = (const float4*)ln[nl + 8];
    const float4* ln4_3 = (const float4*)ln[nl + 12];
    for (int kq = 0; kq < DIN / 4; ++kq) {
        float w0 = w1s[(4 * kq + 0) * HD + j];
        float w1v = w1s[(4 * kq + 1) * HD + j];
        float w2v = w1s[(4 * kq + 2) * HD + j];
        float w3v = w1s[(4 * kq + 3) * HD + j];
        float4 l0 = ln4_0[kq], l1 = ln4_1[kq], l2 = ln4_2[kq], l3 = ln4_3[kq];
        a0 += l0.x * w0 + l0.y * w1v + l0.z * w2v + l0.w * w3v;
        a1 += l1.x * w0 + l1.y * w1v + l1.z * w2v + l1.w * w3v;
        a2 += l2.x * w0 + l2.y * w1v + l2.z * w2v + l2.w * w3v;
        a3 += l3.x * w0 + l3.y * w1v + l3.z * w2v + l3.w * w3v;
    }
    msgn[(size_t)(n0 + nl) * HD + j]      = fmaxf(fmaf(a0, sc_m[j], sh_m[j]), 0.f);
    msgn[(size_t)(n0 + nl + 4) * HD + j]  = fmaxf(fmaf(a1, sc_m[j], sh_m[j]), 0.f);
    msgn[(size_t)(n0 + nl + 8) * HD + j]  = fmaxf(fmaf(a2, sc_m[j], sh_m[j]), 0.f);
    msgn[(size_t)(n0 + nl + 12) * HD + j] = fmaxf(fmaf(a3, sc_m[j], sh_m[j]), 0.f);
}

// ---------------- kernel B: hidden[e] = relu(edge_input[e] @ kw1 + kb1) ------------------
__global__ __launch_bounds__(256) void k_hidden(
    const float* __restrict__ ei, const float* __restrict__ kw1, const float* __restrict__ kb1,
    float* __restrict__ hidden)
{
    __shared__ __align__(16) float kw1s[DE * KHD];    // 16 KB, [c][h]
    __shared__ __align__(16) float eis[32][DE];       // 16 KB
    const int t = threadIdx.x;
    const int e0 = blockIdx.x * 32;
    for (int i = t; i < DE * KHD; i += 256) kw1s[i] = kw1[i];
    for (int i = t; i < 32 * DE; i += 256) {
        int e = i >> 7, c = i & 127;
        eis[e][c] = ei[(size_t)(e0 + e) * DE + c];
    }
    __syncthreads();
    const int h = t & 31, el = t >> 5;   // el 0..7
    float a0 = kb1[h], a1 = a0, a2 = a0, a3 = a0;
    const float4* e4_0 = (const float4*)eis[el];
    const float4* e4_1 = (const float4*)eis[el + 8];
    const float4* e4_2 = (const float4*)eis[el + 16];
    const float4* e4_3 = (const float4*)eis[el + 24];
    for (int cq = 0; cq < DE / 4; ++cq) {
        float w0 = kw1s[(4 * cq + 0) * KHD + h];
        float w1v = kw1s[(4 * cq + 1) * KHD + h];
        float w2v = kw1s[(4 * cq + 2) * KHD + h];
        float w3v = kw1s[(4 * cq + 3) * KHD + h];
        float4 l0 = e4_0[cq], l1 = e4_1[cq], l2 = e4_2[cq], l3 = e4_3[cq];
        a0 += l0.x * w0 + l0.y * w1v + l0.z * w2v + l0.w * w3v;
        a1 += l1.x * w0 + l1.y * w1v + l1.z * w2v + l1.w * w3v;
        a2 += l2.x * w0 + l2.y * w1v + l2.z * w2v + l2.w * w3v;
        a3 += l3.x * w0 + l3.y * w1v + l3.z * w2v + l3.w * w3v;
    }
    hidden[(size_t)(e0 + el) * KHD + h]      = fmaxf(a0, 0.f);
    hidden[(size_t)(e0 + el + 8) * KHD + h]  = fmaxf(a1, 0.f);
    hidden[(size_t)(e0 + el + 16) * KHD + h] = fmaxf(a2, 0.f);
    hidden[(size_t)(e0 + el + 24) * KHD + h] = fmaxf(a3, 0.f);
}

// ---------------- kernel D: fused per-edge bilinear + scatter ----------------------------
// out[e,j] = sum_{h<33} hid_ext[e,h] * ( sum_k kw2ext[h,(1+j)*64+k]*msg[e,k] + kw2ext[h,j] )
// hid_ext row 32 = 1.0, kw2ext row 32 = kb2.  Scatter: update[no[e]] += out[e]*ew[e].
#define BE   256
#define MPAD 68   // 17 float4
#define WPAD 68
__global__ __launch_bounds__(256) void k_edge(
    const float* __restrict__ msgn, const float* __restrict__ hidden,
    const int* __restrict__ elist, const float* __restrict__ eweight,
    const float* __restrict__ kw2, const float* __restrict__ kb2,
    float* __restrict__ update)
{
    __shared__ __align__(16) float m_tile[BE * MPAD];   // 69.6 KB
    __shared__ __align__(16) float wb[2][64 * WPAD];    // 34.8 KB
    __shared__ __align__(16) float hid[BE * 34];        // 34.8 KB
    __shared__ __align__(16) float w0s[33 * 64];        // 8.4 KB
    const int t = threadIdx.x;
    const int e0 = blockIdx.x * BE;

    for (int i = t; i < BE * 64; i += 256) {
        int e = i >> 6, kk = i & 63;
        int ni = elist[(size_t)(e0 + e) * 2];
        m_tile[e * MPAD + kk] = msgn[(size_t)ni * HD + kk];
    }
    for (int i = t; i < BE * KHD; i += 256) {
        int e = i >> 5, hh = i & 31;
        hid[e * 34 + hh] = hidden[(size_t)(e0 + e) * KHD + hh];
    }
    for (int i = t; i < BE; i += 256) hid[i * 34 + 32] = 1.0f;
    for (int i = t; i < 33 * 64; i += 256) {
        int hh = i >> 6, j = i & 63;
        w0s[i] = (hh < 32) ? kw2[(size_t)hh * 4160 + j] : kb2[j];
    }
    // prologue: stage h=0 row block (cols 64..4159 of kw2 row 0)
    for (int i = t; i < 64 * 64; i += 256) {
        int j = i >> 6, kk = i & 63;
        wb[0][j * WPAD + kk] = kw2[64 + i];
    }
    __syncthreads();

    const int tj = t & 7;    // j base: j = tj + 8q
    const int te = t >> 3;   // 0..31: e = te + 32i
    float acc[8][8];
#pragma unroll
    for (int i = 0; i < 8; ++i)
#pragma unroll
        for (int q = 0; q < 8; ++q) acc[i][q] = 0.f;

    for (int h = 0; h < 33; ++h) {
        if (h < 32) {   // stage next h (issue loads early; hidden under compute)
            const float* src = (h + 1 < 32) ? (kw2 + (size_t)(h + 1) * 4160 + 64) : (kb2 + 64);
            float* dst = wb[(h + 1) & 1];
#pragma unroll
            for (int i = t; i < 64 * 64; i += 256) {
                int j = i >> 6, kk = i & 63;
                dst[j * WPAD + kk] = src[i];
            }
        }
        float hv[8];
#pragma unroll
        for (int i = 0; i < 8; ++i) hv[i] = hid[(te + 32 * i) * 34 + h];
        const float4* wbv = (const float4*)wb[h & 1];
        const float4* mv  = (const float4*)m_tile;
#pragma unroll
        for (int kq = 0; kq < 16; ++kq) {
            float4 a[8], b[8];
#pragma unroll
            for (int i = 0; i < 8; ++i) {
                float4 mm = mv[(te + 32 * i) * 17 + kq];
                a[i].x = mm.x * hv[i]; a[i].y = mm.y * hv[i];
                a[i].z = mm.z * hv[i]; a[i].w = mm.w * hv[i];
            }
#pragma unroll
            for (int q = 0; q < 8; ++q) b[q] = wbv[(tj + 8 * q) * 17 + kq];
#pragma unroll
            for (int i = 0; i < 8; ++i)
#pragma unroll
                for (int q = 0; q < 8; ++q)
                    acc[i][q] += a[i].x * b[q].x + a[i].y * b[q].y
                               + a[i].z * b[q].z + a[i].w * b[q].w;
        }
#pragma unroll
        for (int q = 0; q < 8; ++q) {   // r=0 column block term
            float wq = w0s[h * 64 + tj + 8 * q];
#pragma unroll
            for (int i = 0; i < 8; ++i) acc[i][q] = fmaf(hv[i], wq, acc[i][q]);
        }
        __syncthreads();
    }
#pragma unroll
    for (int i = 0; i < 8; ++i) {
        int e = e0 + te + 32 * i;
        float w = eweight[e];
        int no = elist[(size_t)e * 2 + 1];
        float* dstrow = update + (size_t)no * HD;
#pragma unroll
        for (int q = 0; q < 8; ++q)
            atomicAdd(&dstrow[tj + 8 * q], acc[i][q] * w);
    }
}

// ---------------- kernel E: out = bn_out(relu(bn_upd(update)) @ w2 + b2) -----------------
__global__ __launch_bounds__(256) void k_out(
    const float* __restrict__ update, const float* __restrict__ w2, const float* __restrict__ b2,
    const float* __restrict__ g_u, const float* __restrict__ be_u,
    const float* __restrict__ m_u, const float* __restrict__ v_u,
    const float* __restrict__ g_o, const float* __restrict__ be_o,
    const float* __restrict__ m_o, const float* __restrict__ v_o,
    float* __restrict__ out)
{
    __shared__ __align__(16) float w2s[HD * DOUT];    // 64 KB, [k][c]
    __shared__ __align__(16) float ut[16 * 65];
    __shared__ float sc_u[HD], sh_u[HD], sc_o[DOUT], sh_o[DOUT];
    const int t = threadIdx.x;
    const int n0 = blockIdx.x * 16;
    {
        float s = g_o[t] * rsqrtf(v_o[t] + BN_EPS);
        sc_o[t] = s; sh_o[t] = be_o[t] - m_o[t] * s;
        if (t < HD) {
            float s2 = g_u[t] * rsqrtf(v_u[t] + BN_EPS);
            sc_u[t] = s2; sh_u[t] = be_u[t] - m_u[t] * s2;
        }
    }
    for (int i = t; i < HD * DOUT; i += 256) w2s[i] = w2[i];
    __syncthreads();
    for (int i = t; i < 16 * HD; i += 256) {
        int n = i >> 6, k = i & 63;
        float v = update[(size_t)(n0 + n) * HD + k];
        ut[n * 65 + k] = fmaxf(fmaf(v, sc_u[k], sh_u[k]), 0.f);
    }
    __syncthreads();
    const int tc = t & 63, tn = t >> 6;  // c-quad = tc*4, n = tn + 4*ii
    const float4* w2v = (const float4*)w2s;
    float4 acc4[4];
#pragma unroll
    for (int ii = 0; ii < 4; ++ii) acc4[ii] = make_float4(0.f, 0.f, 0.f, 0.f);
    for (int k = 0; k < HD; ++k) {
        float4 w = w2v[k * 64 + tc];
#pragma unroll
        for (int ii = 0; ii < 4; ++ii) {
            float u = ut[(tn + 4 * ii) * 65 + k];
            acc4[ii].x = fmaf(u, w.x, acc4[ii].x);
            acc4[ii].y = fmaf(u, w.y, acc4[ii].y);
            acc4[ii].z = fmaf(u, w.z, acc4[ii].z);
            acc4[ii].w = fmaf(u, w.w, acc4[ii].w);
        }
    }
    const int c = tc * 4;
#pragma unroll
    for (int ii = 0; ii < 4; ++ii) {
        int n = tn + 4 * ii;
        float4 o;
        o.x = fmaf(acc4[ii].x + b2[c + 0], sc_o[c + 0], sh_o[c + 0]);
        o.y = fmaf(acc4[ii].y + b2[c + 1], sc_o[c + 1], sh_o[c + 1]);
        o.z = fmaf(acc4[ii].z + b2[c + 2], sc_o[c + 2], sh_o[c + 2]);
        o.w = fmaf(acc4[ii].w + b2[c + 3], sc_o[c + 3], sh_o[c + 3]);
        *(float4*)(&out[(size_t)(n0 + n) * DOUT + c]) = o;
    }
}

extern "C" void kernel_launch(void* const* d_in, const int* in_sizes, int n_in,
                              void* d_out, int out_size, void* d_ws, size_t ws_size,
                              hipStream_t stream)
{
    (void)in_sizes; (void)n_in; (void)out_size; (void)ws_size;
    const float* x    = (const float*)d_in[0];
    const float* ei   = (const float*)d_in[1];
    const int*   el   = (const int*)  d_in[2];
    const float* ew   = (const float*)d_in[3];
    const float* w1   = (const float*)d_in[4];
    const float* b1   = (const float*)d_in[5];
    const float* kw1  = (const float*)d_in[6];
    const float* kb1  = (const float*)d_in[7];
    const float* kw2  = (const float*)d_in[8];
    const float* kb2  = (const float*)d_in[9];
    const float* w2   = (const float*)d_in[10];
    const float* b2   = (const float*)d_in[11];
    const float* g_in = (const float*)d_in[12], *be_in = (const float*)d_in[13];
    const float* m_in = (const float*)d_in[14], *v_in  = (const float*)d_in[15];
    const float* g_m  = (const float*)d_in[16], *be_m  = (const float*)d_in[17];
    const float* m_m  = (const float*)d_in[18], *v_m   = (const float*)d_in[19];
    const float* g_u  = (const float*)d_in[20], *be_u  = (const float*)d_in[21];
    const float* m_u  = (const float*)d_in[22], *v_u   = (const float*)d_in[23];
    const float* g_o  = (const float*)d_in[24], *be_o  = (const float*)d_in[25];
    const float* m_o  = (const float*)d_in[26], *v_o   = (const float*)d_in[27];

    float* ws     = (float*)d_ws;
    float* msgn   = ws;                                  // N*64
    float* hidden = ws + (size_t)NN * HD;                // E*32
    float* upd    = hidden + (size_t)NE * KHD;           // N*64

    hipMemsetAsync(upd, 0, (size_t)NN * HD * sizeof(float), stream);
    hipLaunchKernelGGL(k_msgn, dim3(NN / 16), dim3(256), 0, stream,
                       x, w1, b1, g_in, be_in, m_in, v_in, g_m, be_m, m_m, v_m, msgn);
    hipLaunchKernelGGL(k_hidden, dim3(NE / 32), dim3(256), 0, stream,
                       ei, kw1, kb1, hidden);
    hipLaunchKernelGGL(k_edge, dim3(NE / BE), dim3(256), 0, stream,
                       msgn, hidden, el, ew, kw2, kb2, upd);
    hipLaunchKernelGGL(k_out, dim3(NN / 16), dim3(256), 0, stream,
                       upd, w2, b2, g_u, be_u, m_u, v_u, g_o, be_o, m_o, v_o, (float*)d_out);
}

// Round 2
// 205.512 us; speedup vs baseline: 8.5019x; 8.5019x over previous
//
#include <hip/hip_runtime.h>

#define NN   16000
#define NE   64000
#define DIN  256
#define HD   64
#define DOUT 256
#define DE   128
#define KHD  32
#define BN_EPS 1e-5f

typedef __attribute__((ext_vector_type(8))) short bf16x8;
typedef __attribute__((ext_vector_type(4))) float f32x4;

__device__ __forceinline__ unsigned short f2bf(float f) {
    unsigned int u = __float_as_uint(f);
    u += 0x7fff + ((u >> 16) & 1);
    return (unsigned short)(u >> 16);
}
__device__ __forceinline__ float bf2f(unsigned short s) {
    return __uint_as_float(((unsigned int)s) << 16);
}

// ---------------- kernel A: msgn_b[n] = bf16( relu(bn_msg(relu(bn_in(x[n])) @ w1 + b1)) ) ----
__global__ __launch_bounds__(256) void k_msgn(
    const float* __restrict__ x, const float* __restrict__ w1, const float* __restrict__ b1,
    const float* __restrict__ g_in, const float* __restrict__ be_in,
    const float* __restrict__ m_in, const float* __restrict__ v_in,
    const float* __restrict__ g_m, const float* __restrict__ be_m,
    const float* __restrict__ m_m, const float* __restrict__ v_m,
    unsigned short* __restrict__ msgn_b)
{
    __shared__ __align__(16) float w1s[DIN * HD];
    __shared__ __align__(16) float ln[16][DIN];
    __shared__ float sc_in[DIN], sh_in[DIN], sc_m[HD], sh_m[HD];
    const int t = threadIdx.x;
    const int n0 = blockIdx.x * 16;
    {
        float s = g_in[t] * rsqrtf(v_in[t] + BN_EPS);
        sc_in[t] = s; sh_in[t] = be_in[t] - m_in[t] * s;
        if (t < HD) {
            float s2 = g_m[t] * rsqrtf(v_m[t] + BN_EPS);
            sc_m[t] = s2; sh_m[t] = be_m[t] - m_m[t] * s2;
        }
    }
    for (int i = t; i < DIN * HD; i += 256) w1s[i] = w1[i];
    __syncthreads();
    for (int i = t; i < 16 * DIN; i += 256) {
        int r = i >> 8, c = i & 255;
        float v = x[(size_t)(n0 + r) * DIN + c];
        ln[r][c] = fmaxf(fmaf(v, sc_in[c], sh_in[c]), 0.f);
    }
    __syncthreads();
    const int j = t & 63, nl = t >> 6;
    float a0 = b1[j], a1 = a0, a2 = a0, a3 = a0;
    const float4* ln4_0 = (const float4*)ln[nl];
    const float4* ln4_1 = (const float4*)ln[nl + 4];
    const float4* ln4_2 = (const float4*)ln[nl + 8];
    const float4* ln4_3 = (const float4*)ln[nl + 12];
    for (int kq = 0; kq < DIN / 4; ++kq) {
        float w0 = w1s[(4 * kq + 0) * HD + j];
        float w1v = w1s[(4 * kq + 1) * HD + j];
        float w2v = w1s[(4 * kq + 2) * HD + j];
        float w3v = w1s[(4 * kq + 3) * HD + j];
        float4 l0 = ln4_0[kq], l1 = ln4_1[kq], l2 = ln4_2[kq], l3 = ln4_3[kq];
        a0 += l0.x * w0 + l0.y * w1v + l0.z * w2v + l0.w * w3v;
        a1 += l1.x * w0 + l1.y * w1v + l1.z * w2v + l1.w * w3v;
        a2 += l2.x * w0 + l2.y * w1v + l2.z * w2v + l2.w * w3v;
        a3 += l3.x * w0 + l3.y * w1v + l3.z * w2v + l3.w * w3v;
    }
    msgn_b[(size_t)(n0 + nl) * HD + j]      = f2bf(fmaxf(fmaf(a0, sc_m[j], sh_m[j]), 0.f));
    msgn_b[(size_t)(n0 + nl + 4) * HD + j]  = f2bf(fmaxf(fmaf(a1, sc_m[j], sh_m[j]), 0.f));
    msgn_b[(size_t)(n0 + nl + 8) * HD + j]  = f2bf(fmaxf(fmaf(a2, sc_m[j], sh_m[j]), 0.f));
    msgn_b[(size_t)(n0 + nl + 12) * HD + j] = f2bf(fmaxf(fmaf(a3, sc_m[j], sh_m[j]), 0.f));
}

// ---------------- kernel B: hid_b[e] = bf16( relu(edge_input[e] @ kw1 + kb1) ) ---------------
__global__ __launch_bounds__(256) void k_hidden(
    const float* __restrict__ ei, const float* __restrict__ kw1, const float* __restrict__ kb1,
    unsigned short* __restrict__ hid_b)
{
    __shared__ __align__(16) float kw1s[DE * KHD];
    __shared__ __align__(16) float eis[32][DE];
    const int t = threadIdx.x;
    const int e0 = blockIdx.x * 32;
    for (int i = t; i < DE * KHD; i += 256) kw1s[i] = kw1[i];
    for (int i = t; i < 32 * DE; i += 256) {
        int e = i >> 7, c = i & 127;
        eis[e][c] = ei[(size_t)(e0 + e) * DE + c];
    }
    __syncthreads();
    const int h = t & 31, el = t >> 5;
    float a0 = kb1[h], a1 = a0, a2 = a0, a3 = a0;
    const float4* e4_0 = (const float4*)eis[el];
    const float4* e4_1 = (const float4*)eis[el + 8];
    const float4* e4_2 = (const float4*)eis[el + 16];
    const float4* e4_3 = (const float4*)eis[el + 24];
    for (int cq = 0; cq < DE / 4; ++cq) {
        float w0 = kw1s[(4 * cq + 0) * KHD + h];
        float w1v = kw1s[(4 * cq + 1) * KHD + h];
        float w2v = kw1s[(4 * cq + 2) * KHD + h];
        float w3v = kw1s[(4 * cq + 3) * KHD + h];
        float4 l0 = e4_0[cq], l1 = e4_1[cq], l2 = e4_2[cq], l3 = e4_3[cq];
        a0 += l0.x * w0 + l0.y * w1v + l0.z * w2v + l0.w * w3v;
        a1 += l1.x * w0 + l1.y * w1v + l1.z * w2v + l1.w * w3v;
        a2 += l2.x * w0 + l2.y * w1v + l2.z * w2v + l2.w * w3v;
        a3 += l3.x * w0 + l3.y * w1v + l3.z * w2v + l3.w * w3v;
    }
    hid_b[(size_t)(e0 + el) * KHD + h]      = f2bf(fmaxf(a0, 0.f));
    hid_b[(size_t)(e0 + el + 8) * KHD + h]  = f2bf(fmaxf(a1, 0.f));
    hid_b[(size_t)(e0 + el + 16) * KHD + h] = f2bf(fmaxf(a2, 0.f));
    hid_b[(size_t)(e0 + el + 24) * KHD + h] = f2bf(fmaxf(a3, 0.f));
}

// ---------------- kernel P: pack kw2/kb2 into bf16 MFMA-friendly layouts --------------------
// Wb[h][j][k] = kw2ext[h][(1+j)*64+k]  (h=32 row is kb2), 33*64*64
// W0b[j][h]   = kw2[h][j]              (64*32)
__global__ __launch_bounds__(256) void k_prep(
    const float* __restrict__ kw2, const float* __restrict__ kb2,
    unsigned short* __restrict__ Wb, unsigned short* __restrict__ W0b)
{
    int idx = blockIdx.x * 256 + threadIdx.x;
    if (idx < 33 * 4096) {
        int h = idx >> 12, r = idx & 4095;  // r = j*64+k
        float v = (h < 32) ? kw2[(size_t)h * 4160 + 64 + r] : kb2[64 + r];
        Wb[idx] = f2bf(v);
    } else if (idx < 33 * 4096 + 64 * KHD) {
        int i2 = idx - 33 * 4096;
        int j = i2 >> 5, h = i2 & 31;
        W0b[i2] = f2bf(kw2[(size_t)h * 4160 + j]);
    }
}

// ---------------- CSR build --------------------------------------------------------------
__global__ __launch_bounds__(256) void k_deg(const int* __restrict__ elist, int* __restrict__ deg) {
    int e = blockIdx.x * 256 + threadIdx.x;
    if (e < NE) atomicAdd(&deg[elist[(size_t)e * 2 + 1]], 1);
}

__global__ __launch_bounds__(1024) void k_scan(const int* __restrict__ deg,
                                               int* __restrict__ rowptr, int* __restrict__ cursor) {
    __shared__ int part[1024];
    const int t = threadIdx.x;
    const int base = t * 16;
    int loc[16]; int s = 0;
#pragma unroll
    for (int i = 0; i < 16; ++i) {
        int idx = base + i;
        int v = (idx < NN) ? deg[idx] : 0;
        loc[i] = s; s += v;
    }
    part[t] = s;
    __syncthreads();
    for (int off = 1; off < 1024; off <<= 1) {
        int v = (t >= off) ? part[t - off] : 0;
        __syncthreads();
        part[t] += v;
        __syncthreads();
    }
    int pre = (t == 0) ? 0 : part[t - 1];
#pragma unroll
    for (int i = 0; i < 16; ++i) {
        int idx = base + i;
        if (idx < NN) { rowptr[idx] = pre + loc[i]; cursor[idx] = pre + loc[i]; }
    }
    if (t == 1023) rowptr[NN] = part[1023];
}

__global__ __launch_bounds__(256) void k_place(const int* __restrict__ elist,
                                               int* __restrict__ cursor, int* __restrict__ eidx) {
    int e = blockIdx.x * 256 + threadIdx.x;
    if (e < NE) {
        int n = elist[(size_t)e * 2 + 1];
        int pos = atomicAdd(&cursor[n], 1);
        eidx[pos] = e;
    }
}

// ---------------- kernel D: fused bilinear via MFMA, per-edge msg_out --------------------
// One wave per 64 edges. C = A*B: A = Wh [j][k] (m=j), B = msg [e][k] (n=e).
// D layout: col = e = lane&15, row = j = (lane>>4)*4 + i.
__global__ __launch_bounds__(64) void k_edge(
    const unsigned short* __restrict__ msgn_b,   // [NN][64]
    const unsigned short* __restrict__ hid_b,    // [NE][32]
    const int* __restrict__ elist, const float* __restrict__ eweight,
    const unsigned short* __restrict__ Wb,       // [33][64][64]
    const unsigned short* __restrict__ W0b,      // [64][32]
    const float* __restrict__ kb2,
    unsigned short* __restrict__ msg_out)        // [NE][64] bf16
{
    __shared__ float hids[64 * 33];
    const int t = threadIdx.x;
    const int g = t >> 4, le = t & 15;
    const int e0 = blockIdx.x * 64;

    for (int i = t; i < 64 * KHD; i += 64) {
        int e = i >> 5, h = i & 31;
        hids[e * 33 + h] = bf2f(hid_b[(size_t)(e0 + e) * KHD + h]);
    }
    hids[t * 33 + 32] = 1.0f;

    int eid[4], ni[4];
#pragma unroll
    for (int nt = 0; nt < 4; ++nt) {
        eid[nt] = e0 + nt * 16 + le;
        ni[nt] = elist[(size_t)eid[nt] * 2];
    }
    bf16x8 bm[4][2];
#pragma unroll
    for (int nt = 0; nt < 4; ++nt)
#pragma unroll
        for (int ks = 0; ks < 2; ++ks)
            bm[nt][ks] = *(const bf16x8*)(msgn_b + (size_t)ni[nt] * HD + ks * 32 + g * 8);
    __syncthreads();

    const f32x4 zz = {0.f, 0.f, 0.f, 0.f};
    f32x4 acc[4][4];
    {   // r=0 block: acc = W0^T-style GEMM: A[j][h]=kw2[h,j], B[h][e]=hid
        bf16x8 hb[4];
#pragma unroll
        for (int nt = 0; nt < 4; ++nt)
            hb[nt] = *(const bf16x8*)(hid_b + (size_t)eid[nt] * KHD + g * 8);
#pragma unroll
        for (int jt = 0; jt < 4; ++jt) {
            bf16x8 a0 = *(const bf16x8*)(W0b + (jt * 16 + le) * KHD + g * 8);
#pragma unroll
            for (int nt = 0; nt < 4; ++nt)
                acc[jt][nt] = __builtin_amdgcn_mfma_f32_16x16x32_bf16(a0, hb[nt], zz, 0, 0, 0);
        }
    }

    for (int h = 0; h < 33; ++h) {
        float hv[4];
#pragma unroll
        for (int nt = 0; nt < 4; ++nt)
            hv[nt] = hids[(nt * 16 + le) * 33 + h];
        const unsigned short* wh = Wb + (size_t)h * 4096;
#pragma unroll
        for (int jt = 0; jt < 4; ++jt) {
            bf16x8 a0 = *(const bf16x8*)(wh + (jt * 16 + le) * 64 + g * 8);
            bf16x8 a1 = *(const bf16x8*)(wh + (jt * 16 + le) * 64 + 32 + g * 8);
#pragma unroll
            for (int nt = 0; nt < 4; ++nt) {
                f32x4 c = __builtin_amdgcn_mfma_f32_16x16x32_bf16(a0, bm[nt][0], zz, 0, 0, 0);
                c = __builtin_amdgcn_mfma_f32_16x16x32_bf16(a1, bm[nt][1], c, 0, 0, 0);
                acc[jt][nt] += hv[nt] * c;
            }
        }
    }

    float ewv[4];
#pragma unroll
    for (int nt = 0; nt < 4; ++nt) ewv[nt] = eweight[eid[nt]];
#pragma unroll
    for (int jt = 0; jt < 4; ++jt)
#pragma unroll
        for (int i = 0; i < 4; ++i) {
            int j = jt * 16 + g * 4 + i;
            float kb = kb2[j];
#pragma unroll
            for (int nt = 0; nt < 4; ++nt)
                msg_out[(size_t)eid[nt] * HD + j] = f2bf((acc[jt][nt][i] + kb) * ewv[nt]);
        }
}

// ---------------- kernel E: gather-sum (CSR) + bn_upd/relu + GEMM + bn_out ----------------
__global__ __launch_bounds__(256) void k_out(
    const unsigned short* __restrict__ msg_out,
    const int* __restrict__ rowptr, const int* __restrict__ eidx,
    const float* __restrict__ w2, const float* __restrict__ b2,
    const float* __restrict__ g_u, const float* __restrict__ be_u,
    const float* __restrict__ m_u, const float* __restrict__ v_u,
    const float* __restrict__ g_o, const float* __restrict__ be_o,
    const float* __restrict__ m_o, const float* __restrict__ v_o,
    float* __restrict__ out)
{
    __shared__ __align__(16) float w2s[HD * DOUT];
    __shared__ __align__(16) float ut[16 * 65];
    __shared__ float sc_u[HD], sh_u[HD], sc_o[DOUT], sh_o[DOUT];
    const int t = threadIdx.x;
    const int n0 = blockIdx.x * 16;
    {
        float s = g_o[t] * rsqrtf(v_o[t] + BN_EPS);
        sc_o[t] = s; sh_o[t] = be_o[t] - m_o[t] * s;
        if (t < HD) {
            float s2 = g_u[t] * rsqrtf(v_u[t] + BN_EPS);
            sc_u[t] = s2; sh_u[t] = be_u[t] - m_u[t] * s2;
        }
    }
    for (int i = t; i < HD * DOUT; i += 256) w2s[i] = w2[i];
    __syncthreads();
    {
        const int j = t & 63, w = t >> 6;
        for (int r = w; r < 16; r += 4) {
            int n = n0 + r;
            int p0 = rowptr[n], p1 = rowptr[n + 1];
            float a = 0.f;
            for (int p = p0; p < p1; ++p)
                a += bf2f(msg_out[(size_t)eidx[p] * HD + j]);
            ut[r * 65 + j] = fmaxf(fmaf(a, sc_u[j], sh_u[j]), 0.f);
        }
    }
    __syncthreads();
    const int tc = t & 63, tn = t >> 6;
    const float4* w2v = (const float4*)w2s;
    float4 acc4[4];
#pragma unroll
    for (int ii = 0; ii < 4; ++ii) acc4[ii] = make_float4(0.f, 0.f, 0.f, 0.f);
    for (int k = 0; k < HD; ++k) {
        float4 w = w2v[k * 64 + tc];
#pragma unroll
        for (int ii = 0; ii < 4; ++ii) {
            float u = ut[(tn + 4 * ii) * 65 + k];
            acc4[ii].x = fmaf(u, w.x, acc4[ii].x);
            acc4[ii].y = fmaf(u, w.y, acc4[ii].y);
            acc4[ii].z = fmaf(u, w.z, acc4[ii].z);
            acc4[ii].w = fmaf(u, w.w, acc4[ii].w);
        }
    }
    const int c = tc * 4;
#pragma unroll
    for (int ii = 0; ii < 4; ++ii) {
        int n = tn + 4 * ii;
        float4 o;
        o.x = fmaf(acc4[ii].x + b2[c + 0], sc_o[c + 0], sh_o[c + 0]);
        o.y = fmaf(acc4[ii].y + b2[c + 1], sc_o[c + 1], sh_o[c + 1]);
        o.z = fmaf(acc4[ii].z + b2[c + 2], sc_o[c + 2], sh_o[c + 2]);
        o.w = fmaf(acc4[ii].w + b2[c + 3], sc_o[c + 3], sh_o[c + 3]);
        *(float4*)(&out[(size_t)(n0 + n) * DOUT + c]) = o;
    }
}

extern "C" void kernel_launch(void* const* d_in, const int* in_sizes, int n_in,
                              void* d_out, int out_size, void* d_ws, size_t ws_size,
                              hipStream_t stream)
{
    (void)in_sizes; (void)n_in; (void)out_size; (void)ws_size;
    const float* x    = (const float*)d_in[0];
    const float* ei   = (const float*)d_in[1];
    const int*   el   = (const int*)  d_in[2];
    const float* ew   = (const float*)d_in[3];
    const float* w1   = (const float*)d_in[4];
    const float* b1   = (const float*)d_in[5];
    const float* kw1  = (const float*)d_in[6];
    const float* kb1  = (const float*)d_in[7];
    const float* kw2  = (const float*)d_in[8];
    const float* kb2  = (const float*)d_in[9];
    const float* w2   = (const float*)d_in[10];
    const float* b2   = (const float*)d_in[11];
    const float* g_in = (const float*)d_in[12], *be_in = (const float*)d_in[13];
    const float* m_in = (const float*)d_in[14], *v_in  = (const float*)d_in[15];
    const float* g_m  = (const float*)d_in[16], *be_m  = (const float*)d_in[17];
    const float* m_m  = (const float*)d_in[18], *v_m   = (const float*)d_in[19];
    const float* g_u  = (const float*)d_in[20], *be_u  = (const float*)d_in[21];
    const float* m_u  = (const float*)d_in[22], *v_u   = (const float*)d_in[23];
    const float* g_o  = (const float*)d_in[24], *be_o  = (const float*)d_in[25];
    const float* m_o  = (const float*)d_in[26], *v_o   = (const float*)d_in[27];

    char* wsb = (char*)d_ws;
    size_t off = 0;
    auto alloc = [&](size_t bytes) -> void* {
        void* p = wsb + off; off += (bytes + 255) & ~(size_t)255; return p;
    };
    unsigned short* msgn_b  = (unsigned short*)alloc((size_t)NN * HD * 2);
    unsigned short* hid_b   = (unsigned short*)alloc((size_t)NE * KHD * 2);
    unsigned short* Wb      = (unsigned short*)alloc((size_t)33 * 4096 * 2);
    unsigned short* W0b     = (unsigned short*)alloc((size_t)64 * KHD * 2);
    unsigned short* msg_out = (unsigned short*)alloc((size_t)NE * HD * 2);
    int* deg    = (int*)alloc((size_t)NN * 4);
    int* cursor = (int*)alloc((size_t)NN * 4);
    int* rowptr = (int*)alloc((size_t)(NN + 1) * 4);
    int* eidx   = (int*)alloc((size_t)NE * 4);

    hipMemsetAsync(deg, 0, (size_t)NN * 4, stream);
    hipLaunchKernelGGL(k_prep, dim3((33 * 4096 + 64 * KHD + 255) / 256), dim3(256), 0, stream,
                       kw2, kb2, Wb, W0b);
    hipLaunchKernelGGL(k_msgn, dim3(NN / 16), dim3(256), 0, stream,
                       x, w1, b1, g_in, be_in, m_in, v_in, g_m, be_m, m_m, v_m, msgn_b);
    hipLaunchKernelGGL(k_hidden, dim3(NE / 32), dim3(256), 0, stream,
                       ei, kw1, kb1, hid_b);
    hipLaunchKernelGGL(k_deg, dim3(NE / 256), dim3(256), 0, stream, el, deg);
    hipLaunchKernelGGL(k_scan, dim3(1), dim3(1024), 0, stream, deg, rowptr, cursor);
    hipLaunchKernelGGL(k_place, dim3(NE / 256), dim3(256), 0, stream, el, cursor, eidx);
    hipLaunchKernelGGL(k_edge, dim3(NE / 64), dim3(64), 0, stream,
                       msgn_b, hid_b, el, ew, Wb, W0b, kb2, msg_out);
    hipLaunchKernelGGL(k_out, dim3(NN / 16), dim3(256), 0, stream,
                       msg_out, rowptr, eidx, w2, b2, g_u, be_u, m_u, v_u,
                       g_o, be_o, m_o, v_o, (float*)d_out);
}

// Round 3
// 151.575 us; speedup vs baseline: 11.5272x; 1.3558x over previous
//
#include <hip/hip_runtime.h>

#define NN   16000
#define NE   64000
#define DIN  256
#define HD   64
#define DOUT 256
#define DE   128
#define KHD  32
#define BN_EPS 1e-5f

typedef __attribute__((ext_vector_type(8))) short bf16x8;
typedef __attribute__((ext_vector_type(4))) float f32x4;

__device__ __forceinline__ unsigned short f2bf(float f) {
    unsigned int u = __float_as_uint(f);
    u += 0x7fff + ((u >> 16) & 1);
    return (unsigned short)(u >> 16);
}
__device__ __forceinline__ float bf2f(unsigned short s) {
    return __uint_as_float(((unsigned int)s) << 16);
}

// ---------------- kernel P: pack all weights into bf16 MFMA layouts ----------------------
// Wb[h][j][k]=kw2ext[h][(1+j)*64+k] (h=32 is kb2) | W0b[j][h]=kw2[h][j]
// w1b[j][k]=w1[k][j] | kw1b[h][k]=kw1[k][h] | w2b[c][k]=w2[k][c]
__global__ __launch_bounds__(256) void k_prep(
    const float* __restrict__ kw2, const float* __restrict__ kb2,
    const float* __restrict__ w1, const float* __restrict__ kw1, const float* __restrict__ w2,
    unsigned short* __restrict__ Wb, unsigned short* __restrict__ W0b,
    unsigned short* __restrict__ w1b, unsigned short* __restrict__ kw1b,
    unsigned short* __restrict__ w2b)
{
    int idx = blockIdx.x * 256 + threadIdx.x;
    if (idx < 33 * 4096) {
        int h = idx >> 12, r = idx & 4095;
        float v = (h < 32) ? kw2[(size_t)h * 4160 + 64 + r] : kb2[64 + r];
        Wb[idx] = f2bf(v);
        return;
    }
    idx -= 33 * 4096;
    if (idx < 2048) { int j = idx >> 5, h = idx & 31; W0b[idx] = f2bf(kw2[(size_t)h * 4160 + j]); return; }
    idx -= 2048;
    if (idx < 16384) { int j = idx >> 8, k = idx & 255; w1b[idx] = f2bf(w1[(size_t)k * 64 + j]); return; }
    idx -= 16384;
    if (idx < 4096) { int h = idx >> 7, k = idx & 127; kw1b[idx] = f2bf(kw1[(size_t)k * 32 + h]); return; }
    idx -= 4096;
    if (idx < 16384) { int c = idx >> 6, k = idx & 63; w2b[idx] = f2bf(w2[(size_t)k * 256 + c]); return; }
}

// ---------------- kernel A: msgn_b = bf16(relu(bn_msg(relu(bn_in(x)) @ w1 + b1))) --------
// MFMA: C[j=64][n=64] = w1b[j][k=256] * lnb[n][k=256]; 4 waves, wave w = nodes w*16..
#define LNS 264   // 256 + 8 pad (2-way LDS aliasing only)
__global__ __launch_bounds__(256) void k_msgn(
    const float* __restrict__ x, const unsigned short* __restrict__ w1b,
    const float* __restrict__ b1,
    const float* __restrict__ g_in, const float* __restrict__ be_in,
    const float* __restrict__ m_in, const float* __restrict__ v_in,
    const float* __restrict__ g_m, const float* __restrict__ be_m,
    const float* __restrict__ m_m, const float* __restrict__ v_m,
    unsigned short* __restrict__ msgn_b)
{
    __shared__ __align__(16) unsigned short lnb[64 * LNS];
    __shared__ __align__(16) float sc_in[DIN], sh_in[DIN], sc_m[HD], shm2[HD];
    const int t = threadIdx.x;
    const int n0 = blockIdx.x * 64;
    {
        float s = g_in[t] * rsqrtf(v_in[t] + BN_EPS);
        sc_in[t] = s; sh_in[t] = be_in[t] - m_in[t] * s;
        if (t < HD) {
            float s2 = g_m[t] * rsqrtf(v_m[t] + BN_EPS);
            sc_m[t] = s2; shm2[t] = b1[t] * s2 + (be_m[t] - m_m[t] * s2);
        }
    }
    __syncthreads();
    for (int i = t; i < 64 * 64; i += 256) {
        int row = i >> 6, c4 = (i & 63) * 4;
        float4 xx = *(const float4*)(x + (size_t)(n0 + row) * DIN + c4);
        float4 sc = *(const float4*)(sc_in + c4);
        float4 sh = *(const float4*)(sh_in + c4);
        ushort4 o;
        o.x = f2bf(fmaxf(fmaf(xx.x, sc.x, sh.x), 0.f));
        o.y = f2bf(fmaxf(fmaf(xx.y, sc.y, sh.y), 0.f));
        o.z = f2bf(fmaxf(fmaf(xx.z, sc.z, sh.z), 0.f));
        o.w = f2bf(fmaxf(fmaf(xx.w, sc.w, sh.w), 0.f));
        *(ushort4*)(lnb + row * LNS + c4) = o;
    }
    __syncthreads();
    const int w = t >> 6, le = t & 15, g = (t >> 4) & 3;
    const f32x4 zz = {0.f, 0.f, 0.f, 0.f};
    f32x4 acc[4] = {zz, zz, zz, zz};
#pragma unroll
    for (int ks = 0; ks < 8; ++ks) {
        bf16x8 b = *(const bf16x8*)(lnb + (w * 16 + le) * LNS + ks * 32 + g * 8);
#pragma unroll
        for (int jt = 0; jt < 4; ++jt) {
            bf16x8 a = *(const bf16x8*)(w1b + (jt * 16 + le) * 256 + ks * 32 + g * 8);
            acc[jt] = __builtin_amdgcn_mfma_f32_16x16x32_bf16(a, b, acc[jt], 0, 0, 0);
        }
    }
    const int n = n0 + w * 16 + le;
#pragma unroll
    for (int jt = 0; jt < 4; ++jt) {
        int j = jt * 16 + g * 4;
        float4 sc = *(const float4*)(sc_m + j);
        float4 sh = *(const float4*)(shm2 + j);
        ushort4 o;
        o.x = f2bf(fmaxf(fmaf(acc[jt][0], sc.x, sh.x), 0.f));
        o.y = f2bf(fmaxf(fmaf(acc[jt][1], sc.y, sh.y), 0.f));
        o.z = f2bf(fmaxf(fmaf(acc[jt][2], sc.z, sh.z), 0.f));
        o.w = f2bf(fmaxf(fmaf(acc[jt][3], sc.w, sh.w), 0.f));
        *(ushort4*)(msgn_b + (size_t)n * HD + j) = o;
    }
}

// ---------------- kernel B: hid_b = bf16(relu(ei @ kw1 + kb1)) ---------------------------
// MFMA: C[h=32][e=64] = kw1b[h][k=128] * eib[e][k=128]
#define EIS 136
__global__ __launch_bounds__(256) void k_hidden(
    const float* __restrict__ ei, const unsigned short* __restrict__ kw1b,
    const float* __restrict__ kb1, unsigned short* __restrict__ hid_b)
{
    __shared__ __align__(16) unsigned short eib[64 * EIS];
    __shared__ float kb1s[KHD];
    const int t = threadIdx.x;
    const int e0 = blockIdx.x * 64;
    if (t < KHD) kb1s[t] = kb1[t];
    for (int i = t; i < 64 * 32; i += 256) {
        int row = i >> 5, c4 = (i & 31) * 4;
        float4 xx = *(const float4*)(ei + (size_t)(e0 + row) * DE + c4);
        ushort4 o;
        o.x = f2bf(xx.x); o.y = f2bf(xx.y); o.z = f2bf(xx.z); o.w = f2bf(xx.w);
        *(ushort4*)(eib + row * EIS + c4) = o;
    }
    __syncthreads();
    const int w = t >> 6, le = t & 15, g = (t >> 4) & 3;
    const f32x4 zz = {0.f, 0.f, 0.f, 0.f};
    f32x4 acc[2] = {zz, zz};
#pragma unroll
    for (int ks = 0; ks < 4; ++ks) {
        bf16x8 b = *(const bf16x8*)(eib + (w * 16 + le) * EIS + ks * 32 + g * 8);
#pragma unroll
        for (int jt = 0; jt < 2; ++jt) {
            bf16x8 a = *(const bf16x8*)(kw1b + (jt * 16 + le) * 128 + ks * 32 + g * 8);
            acc[jt] = __builtin_amdgcn_mfma_f32_16x16x32_bf16(a, b, acc[jt], 0, 0, 0);
        }
    }
    const int e = e0 + w * 16 + le;
#pragma unroll
    for (int jt = 0; jt < 2; ++jt) {
        int h = jt * 16 + g * 4;
        ushort4 o;
        o.x = f2bf(fmaxf(acc[jt][0] + kb1s[h + 0], 0.f));
        o.y = f2bf(fmaxf(acc[jt][1] + kb1s[h + 1], 0.f));
        o.z = f2bf(fmaxf(acc[jt][2] + kb1s[h + 2], 0.f));
        o.w = f2bf(fmaxf(acc[jt][3] + kb1s[h + 3], 0.f));
        *(ushort4*)(hid_b + (size_t)e * KHD + h) = o;
    }
}

// ---------------- CSR build --------------------------------------------------------------
__global__ __launch_bounds__(256) void k_deg(const int* __restrict__ elist, int* __restrict__ deg) {
    int e = blockIdx.x * 256 + threadIdx.x;
    if (e < NE) atomicAdd(&deg[elist[(size_t)e * 2 + 1]], 1);
}

__global__ __launch_bounds__(1024) void k_scan(const int* __restrict__ deg,
                                               int* __restrict__ rowptr, int* __restrict__ cursor) {
    __shared__ int part[1024];
    const int t = threadIdx.x;
    const int base = t * 16;
    int loc[16]; int s = 0;
#pragma unroll
    for (int i = 0; i < 16; ++i) {
        int idx = base + i;
        int v = (idx < NN) ? deg[idx] : 0;
        loc[i] = s; s += v;
    }
    part[t] = s;
    __syncthreads();
    for (int off = 1; off < 1024; off <<= 1) {
        int v = (t >= off) ? part[t - off] : 0;
        __syncthreads();
        part[t] += v;
        __syncthreads();
    }
    int pre = (t == 0) ? 0 : part[t - 1];
#pragma unroll
    for (int i = 0; i < 16; ++i) {
        int idx = base + i;
        if (idx < NN) { rowptr[idx] = pre + loc[i]; cursor[idx] = pre + loc[i]; }
    }
    if (t == 1023) rowptr[NN] = part[1023];
}

__global__ __launch_bounds__(256) void k_place(const int* __restrict__ elist,
                                               int* __restrict__ cursor, int* __restrict__ eidx) {
    int e = blockIdx.x * 256 + threadIdx.x;
    if (e < NE) {
        int n = elist[(size_t)e * 2 + 1];
        int pos = atomicAdd(&cursor[n], 1);
        eidx[pos] = e;
    }
}

// ---------------- kernel D: fused bilinear via MFMA (4 waves, wave = j-tile) -------------
#define HS 36
__global__ __launch_bounds__(256) void k_edge(
    const unsigned short* __restrict__ msgn_b,   // [NN][64]
    const unsigned short* __restrict__ hid_b,    // [NE][32]
    const int* __restrict__ elist, const float* __restrict__ eweight,
    const unsigned short* __restrict__ Wb,       // [33][64][64]
    const unsigned short* __restrict__ W0b,      // [64][32]
    const float* __restrict__ kb2,
    unsigned short* __restrict__ msg_out)        // [NE][64] bf16 (pre-scaled by eweight)
{
    __shared__ __align__(16) float hids[64 * HS];
    const int t = threadIdx.x;
    const int w = t >> 6, le = t & 15, g = (t >> 4) & 3;
    const int e0 = blockIdx.x * 64;

    for (int q = t; q < 512; q += 256) {
        int e = q >> 3, h = (q & 7) * 4;
        ushort4 hh = *(const ushort4*)(hid_b + (size_t)(e0 + e) * KHD + h);
        float4 f; f.x = bf2f(hh.x); f.y = bf2f(hh.y); f.z = bf2f(hh.z); f.w = bf2f(hh.w);
        *(float4*)(hids + e * HS + h) = f;
    }
    if (t < 64) hids[t * HS + 32] = 1.0f;

    int eid[4];
#pragma unroll
    for (int nt = 0; nt < 4; ++nt) eid[nt] = e0 + nt * 16 + le;

    bf16x8 bm[4][2];
#pragma unroll
    for (int nt = 0; nt < 4; ++nt) {
        int ni = elist[(size_t)eid[nt] * 2];
#pragma unroll
        for (int ks = 0; ks < 2; ++ks)
            bm[nt][ks] = *(const bf16x8*)(msgn_b + (size_t)ni * HD + ks * 32 + g * 8);
    }

    const f32x4 zz = {0.f, 0.f, 0.f, 0.f};
    f32x4 acc[4];
    {   // r=0 block: A[j][h]=kw2[h,j], B=hid (bf16), K=32
        bf16x8 a0 = *(const bf16x8*)(W0b + (w * 16 + le) * KHD + g * 8);
#pragma unroll
        for (int nt = 0; nt < 4; ++nt) {
            bf16x8 hb = *(const bf16x8*)(hid_b + (size_t)eid[nt] * KHD + g * 8);
            acc[nt] = __builtin_amdgcn_mfma_f32_16x16x32_bf16(a0, hb, zz, 0, 0, 0);
        }
    }
    __syncthreads();

#pragma unroll 3
    for (int h = 0; h < 33; ++h) {
        float hv[4];
#pragma unroll
        for (int nt = 0; nt < 4; ++nt) hv[nt] = hids[(nt * 16 + le) * HS + h];
        const unsigned short* wh = Wb + (size_t)h * 4096 + (w * 16 + le) * 64;
        bf16x8 a0 = *(const bf16x8*)(wh + g * 8);
        bf16x8 a1 = *(const bf16x8*)(wh + 32 + g * 8);
#pragma unroll
        for (int nt = 0; nt < 4; ++nt) {
            f32x4 c = __builtin_amdgcn_mfma_f32_16x16x32_bf16(a0, bm[nt][0], zz, 0, 0, 0);
            c = __builtin_amdgcn_mfma_f32_16x16x32_bf16(a1, bm[nt][1], c, 0, 0, 0);
            acc[nt] += hv[nt] * c;
        }
    }

    const int j = w * 16 + g * 4;
    float4 kbv = *(const float4*)(kb2 + j);
#pragma unroll
    for (int nt = 0; nt < 4; ++nt) {
        float ew = eweight[eid[nt]];
        ushort4 o;
        o.x = f2bf((acc[nt][0] + kbv.x) * ew);
        o.y = f2bf((acc[nt][1] + kbv.y) * ew);
        o.z = f2bf((acc[nt][2] + kbv.z) * ew);
        o.w = f2bf((acc[nt][3] + kbv.w) * ew);
        *(ushort4*)(msg_out + (size_t)eid[nt] * HD + j) = o;
    }
}

// ---------------- kernel E: CSR gather-sum + bn_upd/relu + MFMA GEMM + bn_out ------------
#define UTS 72
__global__ __launch_bounds__(256) void k_out(
    const unsigned short* __restrict__ msg_out,
    const int* __restrict__ rowptr, const int* __restrict__ eidx,
    const unsigned short* __restrict__ w2b, const float* __restrict__ b2,
    const float* __restrict__ g_u, const float* __restrict__ be_u,
    const float* __restrict__ m_u, const float* __restrict__ v_u,
    const float* __restrict__ g_o, const float* __restrict__ be_o,
    const float* __restrict__ m_o, const float* __restrict__ v_o,
    float* __restrict__ out)
{
    __shared__ __align__(16) unsigned short utb[64 * UTS];
    __shared__ __align__(16) float sc_o[DOUT], sho2[DOUT], sc_u[HD], sh_u[HD];
    const int t = threadIdx.x;
    const int n0 = blockIdx.x * 64;
    {
        float s = g_o[t] * rsqrtf(v_o[t] + BN_EPS);
        sc_o[t] = s; sho2[t] = b2[t] * s + (be_o[t] - m_o[t] * s);
        if (t < HD) {
            float s2 = g_u[t] * rsqrtf(v_u[t] + BN_EPS);
            sc_u[t] = s2; sh_u[t] = be_u[t] - m_u[t] * s2;
        }
    }
    __syncthreads();
    {
        const int j = t & 63, qw = t >> 6;
        for (int r = qw; r < 64; r += 4) {
            int n = n0 + r;
            int p0 = rowptr[n], p1 = rowptr[n + 1];
            float a = 0.f;
            for (int p = p0; p < p1; ++p)
                a += bf2f(msg_out[(size_t)eidx[p] * HD + j]);
            utb[r * UTS + j] = f2bf(fmaxf(fmaf(a, sc_u[j], sh_u[j]), 0.f));
        }
    }
    __syncthreads();
    const int w = t >> 6, le = t & 15, g = (t >> 4) & 3;
    const f32x4 zz = {0.f, 0.f, 0.f, 0.f};
    f32x4 acc[4][4];
#pragma unroll
    for (int jt = 0; jt < 4; ++jt)
#pragma unroll
        for (int nt = 0; nt < 4; ++nt) acc[jt][nt] = zz;
#pragma unroll
    for (int ks = 0; ks < 2; ++ks) {
        bf16x8 b[4];
#pragma unroll
        for (int nt = 0; nt < 4; ++nt)
            b[nt] = *(const bf16x8*)(utb + (nt * 16 + le) * UTS + ks * 32 + g * 8);
#pragma unroll
        for (int jt = 0; jt < 4; ++jt) {
            bf16x8 a = *(const bf16x8*)(w2b + (size_t)(w * 64 + jt * 16 + le) * HD + ks * 32 + g * 8);
#pragma unroll
            for (int nt = 0; nt < 4; ++nt)
                acc[jt][nt] = __builtin_amdgcn_mfma_f32_16x16x32_bf16(a, b[nt], acc[jt][nt], 0, 0, 0);
        }
    }
#pragma unroll
    for (int jt = 0; jt < 4; ++jt) {
        int c = w * 64 + jt * 16 + g * 4;
        float4 sc = *(const float4*)(sc_o + c);
        float4 sh = *(const float4*)(sho2 + c);
#pragma unroll
        for (int nt = 0; nt < 4; ++nt) {
            int n = n0 + nt * 16 + le;
            float4 o;
            o.x = fmaf(acc[jt][nt][0], sc.x, sh.x);
            o.y = fmaf(acc[jt][nt][1], sc.y, sh.y);
            o.z = fmaf(acc[jt][nt][2], sc.z, sh.z);
            o.w = fmaf(acc[jt][nt][3], sc.w, sh.w);
            *(float4*)(out + (size_t)n * DOUT + c) = o;
        }
    }
}

extern "C" void kernel_launch(void* const* d_in, const int* in_sizes, int n_in,
                              void* d_out, int out_size, void* d_ws, size_t ws_size,
                              hipStream_t stream)
{
    (void)in_sizes; (void)n_in; (void)out_size; (void)ws_size;
    const float* x    = (const float*)d_in[0];
    const float* ei   = (const float*)d_in[1];
    const int*   el   = (const int*)  d_in[2];
    const float* ew   = (const float*)d_in[3];
    const float* w1   = (const float*)d_in[4];
    const float* b1   = (const float*)d_in[5];
    const float* kw1  = (const float*)d_in[6];
    const float* kb1  = (const float*)d_in[7];
    const float* kw2  = (const float*)d_in[8];
    const float* kb2  = (const float*)d_in[9];
    const float* w2   = (const float*)d_in[10];
    const float* b2   = (const float*)d_in[11];
    const float* g_in = (const float*)d_in[12], *be_in = (const float*)d_in[13];
    const float* m_in = (const float*)d_in[14], *v_in  = (const float*)d_in[15];
    const float* g_m  = (const float*)d_in[16], *be_m  = (const float*)d_in[17];
    const float* m_m  = (const float*)d_in[18], *v_m   = (const float*)d_in[19];
    const float* g_u  = (const float*)d_in[20], *be_u  = (const float*)d_in[21];
    const float* m_u  = (const float*)d_in[22], *v_u   = (const float*)d_in[23];
    const float* g_o  = (const float*)d_in[24], *be_o  = (const float*)d_in[25];
    const float* m_o  = (const float*)d_in[26], *v_o   = (const float*)d_in[27];

    char* wsb = (char*)d_ws;
    size_t off = 0;
    auto alloc = [&](size_t bytes) -> void* {
        void* p = wsb + off; off += (bytes + 255) & ~(size_t)255; return p;
    };
    unsigned short* msgn_b  = (unsigned short*)alloc((size_t)NN * HD * 2);
    unsigned short* hid_b   = (unsigned short*)alloc((size_t)NE * KHD * 2);
    unsigned short* Wb      = (unsigned short*)alloc((size_t)33 * 4096 * 2);
    unsigned short* W0b     = (unsigned short*)alloc((size_t)64 * KHD * 2);
    unsigned short* w1b     = (unsigned short*)alloc((size_t)HD * DIN * 2);
    unsigned short* kw1b    = (unsigned short*)alloc((size_t)KHD * DE * 2);
    unsigned short* w2b     = (unsigned short*)alloc((size_t)DOUT * HD * 2);
    int* rowptr = (int*)alloc((size_t)(NN + 1) * 4);
    int* eidx   = (int*)alloc((size_t)NE * 4);
    // union: deg+cursor live only until k_place; msg_out written after (k_edge)
    char* un = (char*)alloc((size_t)NE * HD * 2);
    unsigned short* msg_out = (unsigned short*)un;
    int* deg    = (int*)un;
    int* cursor = (int*)(un + (((size_t)NN * 4 + 255) & ~(size_t)255));

    hipMemsetAsync(deg, 0, (size_t)NN * 4, stream);
    hipLaunchKernelGGL(k_prep, dim3(680), dim3(256), 0, stream,
                       kw2, kb2, w1, kw1, w2, Wb, W0b, w1b, kw1b, w2b);
    hipLaunchKernelGGL(k_deg, dim3(NE / 256), dim3(256), 0, stream, el, deg);
    hipLaunchKernelGGL(k_scan, dim3(1), dim3(1024), 0, stream, deg, rowptr, cursor);
    hipLaunchKernelGGL(k_place, dim3(NE / 256), dim3(256), 0, stream, el, cursor, eidx);
    hipLaunchKernelGGL(k_msgn, dim3(NN / 64), dim3(256), 0, stream,
                       x, w1b, b1, g_in, be_in, m_in, v_in, g_m, be_m, m_m, v_m, msgn_b);
    hipLaunchKernelGGL(k_hidden, dim3(NE / 64), dim3(256), 0, stream,
                       ei, kw1b, kb1, hid_b);
    hipLaunchKernelGGL(k_edge, dim3(NE / 64), dim3(256), 0, stream,
                       msgn_b, hid_b, el, ew, Wb, W0b, kb2, msg_out);
    hipLaunchKernelGGL(k_out, dim3(NN / 64), dim3(256), 0, stream,
                       msg_out, rowptr, eidx, w2b, b2, g_u, be_u, m_u, v_u,
                       g_o, be_o, m_o, v_o, (float*)d_out);
}

// Round 5
// 137.806 us; speedup vs baseline: 12.6789x; 1.0999x over previous
//
#include <hip/hip_runtime.h>

#define NN   16000
#define NE   64000
#define DIN  256
#define HD   64
#define DOUT 256
#define DE   128
#define KHD  32
#define BN_EPS 1e-5f

typedef __attribute__((ext_vector_type(8))) short bf16x8;
typedef __attribute__((ext_vector_type(4))) float f32x4;

__device__ __forceinline__ unsigned short f2bf(float f) {
    unsigned int u = __float_as_uint(f);
    u += 0x7fff + ((u >> 16) & 1);
    return (unsigned short)(u >> 16);
}
__device__ __forceinline__ float bf2f(unsigned short s) {
    return __uint_as_float(((unsigned int)s) << 16);
}

// ---------------- kernel P: pack all weights into bf16 MFMA layouts ----------------------
__global__ __launch_bounds__(256) void k_prep(
    const float* __restrict__ kw2, const float* __restrict__ kb2,
    const float* __restrict__ w1, const float* __restrict__ kw1, const float* __restrict__ w2,
    unsigned short* __restrict__ Wb, unsigned short* __restrict__ W0b,
    unsigned short* __restrict__ w1b, unsigned short* __restrict__ kw1b,
    unsigned short* __restrict__ w2b)
{
    int idx = blockIdx.x * 256 + threadIdx.x;
    if (idx < 33 * 4096) {
        int h = idx >> 12, r = idx & 4095;
        float v = (h < 32) ? kw2[(size_t)h * 4160 + 64 + r] : kb2[64 + r];
        Wb[idx] = f2bf(v);
        return;
    }
    idx -= 33 * 4096;
    if (idx < 2048) { int j = idx >> 5, h = idx & 31; W0b[idx] = f2bf(kw2[(size_t)h * 4160 + j]); return; }
    idx -= 2048;
    if (idx < 16384) { int j = idx >> 8, k = idx & 255; w1b[idx] = f2bf(w1[(size_t)k * 64 + j]); return; }
    idx -= 16384;
    if (idx < 4096) { int h = idx >> 7, k = idx & 127; kw1b[idx] = f2bf(kw1[(size_t)k * 32 + h]); return; }
    idx -= 4096;
    if (idx < 16384) { int c = idx >> 6, k = idx & 63; w2b[idx] = f2bf(w2[(size_t)k * 256 + c]); return; }
}

// ---------------- kernel A: msgn_b = bf16(relu(bn_msg(relu(bn_in(x)) @ w1 + b1))) --------
#define LNS 264
__global__ __launch_bounds__(256) void k_msgn(
    const float* __restrict__ x, const unsigned short* __restrict__ w1b,
    const float* __restrict__ b1,
    const float* __restrict__ g_in, const float* __restrict__ be_in,
    const float* __restrict__ m_in, const float* __restrict__ v_in,
    const float* __restrict__ g_m, const float* __restrict__ be_m,
    const float* __restrict__ m_m, const float* __restrict__ v_m,
    unsigned short* __restrict__ msgn_b)
{
    __shared__ __align__(16) unsigned short lnb[64 * LNS];
    __shared__ __align__(16) float sc_in[DIN], sh_in[DIN], sc_m[HD], shm2[HD];
    const int t = threadIdx.x;
    const int n0 = blockIdx.x * 64;
    {
        float s = g_in[t] * rsqrtf(v_in[t] + BN_EPS);
        sc_in[t] = s; sh_in[t] = be_in[t] - m_in[t] * s;
        if (t < HD) {
            float s2 = g_m[t] * rsqrtf(v_m[t] + BN_EPS);
            sc_m[t] = s2; shm2[t] = b1[t] * s2 + (be_m[t] - m_m[t] * s2);
        }
    }
    __syncthreads();
    for (int i = t; i < 64 * 64; i += 256) {
        int row = i >> 6, c4 = (i & 63) * 4;
        float4 xx = *(const float4*)(x + (size_t)(n0 + row) * DIN + c4);
        float4 sc = *(const float4*)(sc_in + c4);
        float4 sh = *(const float4*)(sh_in + c4);
        ushort4 o;
        o.x = f2bf(fmaxf(fmaf(xx.x, sc.x, sh.x), 0.f));
        o.y = f2bf(fmaxf(fmaf(xx.y, sc.y, sh.y), 0.f));
        o.z = f2bf(fmaxf(fmaf(xx.z, sc.z, sh.z), 0.f));
        o.w = f2bf(fmaxf(fmaf(xx.w, sc.w, sh.w), 0.f));
        *(ushort4*)(lnb + row * LNS + c4) = o;
    }
    __syncthreads();
    const int w = t >> 6, le = t & 15, g = (t >> 4) & 3;
    const f32x4 zz = {0.f, 0.f, 0.f, 0.f};
    f32x4 acc[4] = {zz, zz, zz, zz};
#pragma unroll
    for (int ks = 0; ks < 8; ++ks) {
        bf16x8 b = *(const bf16x8*)(lnb + (w * 16 + le) * LNS + ks * 32 + g * 8);
#pragma unroll
        for (int jt = 0; jt < 4; ++jt) {
            bf16x8 a = *(const bf16x8*)(w1b + (jt * 16 + le) * 256 + ks * 32 + g * 8);
            acc[jt] = __builtin_amdgcn_mfma_f32_16x16x32_bf16(a, b, acc[jt], 0, 0, 0);
        }
    }
    const int n = n0 + w * 16 + le;
#pragma unroll
    for (int jt = 0; jt < 4; ++jt) {
        int j = jt * 16 + g * 4;
        float4 sc = *(const float4*)(sc_m + j);
        float4 sh = *(const float4*)(shm2 + j);
        ushort4 o;
        o.x = f2bf(fmaxf(fmaf(acc[jt][0], sc.x, sh.x), 0.f));
        o.y = f2bf(fmaxf(fmaf(acc[jt][1], sc.y, sh.y), 0.f));
        o.z = f2bf(fmaxf(fmaf(acc[jt][2], sc.z, sh.z), 0.f));
        o.w = f2bf(fmaxf(fmaf(acc[jt][3], sc.w, sh.w), 0.f));
        *(ushort4*)(msgn_b + (size_t)n * HD + j) = o;
    }
}

// ---------------- kernel B: hid_b = bf16(relu(ei @ kw1 + kb1)) ---------------------------
#define EIS 136
__global__ __launch_bounds__(256) void k_hidden(
    const float* __restrict__ ei, const unsigned short* __restrict__ kw1b,
    const float* __restrict__ kb1, unsigned short* __restrict__ hid_b)
{
    __shared__ __align__(16) unsigned short eib[64 * EIS];
    __shared__ float kb1s[KHD];
    const int t = threadIdx.x;
    const int e0 = blockIdx.x * 64;
    if (t < KHD) kb1s[t] = kb1[t];
    for (int i = t; i < 64 * 32; i += 256) {
        int row = i >> 5, c4 = (i & 31) * 4;
        float4 xx = *(const float4*)(ei + (size_t)(e0 + row) * DE + c4);
        ushort4 o;
        o.x = f2bf(xx.x); o.y = f2bf(xx.y); o.z = f2bf(xx.z); o.w = f2bf(xx.w);
        *(ushort4*)(eib + row * EIS + c4) = o;
    }
    __syncthreads();
    const int w = t >> 6, le = t & 15, g = (t >> 4) & 3;
    const f32x4 zz = {0.f, 0.f, 0.f, 0.f};
    f32x4 acc[2] = {zz, zz};
#pragma unroll
    for (int ks = 0; ks < 4; ++ks) {
        bf16x8 b = *(const bf16x8*)(eib + (w * 16 + le) * EIS + ks * 32 + g * 8);
#pragma unroll
        for (int jt = 0; jt < 2; ++jt) {
            bf16x8 a = *(const bf16x8*)(kw1b + (jt * 16 + le) * 128 + ks * 32 + g * 8);
            acc[jt] = __builtin_amdgcn_mfma_f32_16x16x32_bf16(a, b, acc[jt], 0, 0, 0);
        }
    }
    const int e = e0 + w * 16 + le;
#pragma unroll
    for (int jt = 0; jt < 2; ++jt) {
        int h = jt * 16 + g * 4;
        ushort4 o;
        o.x = f2bf(fmaxf(acc[jt][0] + kb1s[h + 0], 0.f));
        o.y = f2bf(fmaxf(acc[jt][1] + kb1s[h + 1], 0.f));
        o.z = f2bf(fmaxf(acc[jt][2] + kb1s[h + 2], 0.f));
        o.w = f2bf(fmaxf(acc[jt][3] + kb1s[h + 3], 0.f));
        *(ushort4*)(hid_b + (size_t)e * KHD + h) = o;
    }
}

// ---------------- CSR build --------------------------------------------------------------
__global__ __launch_bounds__(256) void k_deg(const int* __restrict__ elist, int* __restrict__ deg) {
    int e = blockIdx.x * 256 + threadIdx.x;
    if (e < NE) atomicAdd(&deg[elist[(size_t)e * 2 + 1]], 1);
}

__global__ __launch_bounds__(1024) void k_scan(const int* __restrict__ deg,
                                               int* __restrict__ rowptr, int* __restrict__ cursor) {
    __shared__ int part[1024];
    const int t = threadIdx.x;
    const int base = t * 16;
    int loc[16]; int s = 0;
#pragma unroll
    for (int i = 0; i < 16; ++i) {
        int idx = base + i;
        int v = (idx < NN) ? deg[idx] : 0;
        loc[i] = s; s += v;
    }
    part[t] = s;
    __syncthreads();
    for (int off = 1; off < 1024; off <<= 1) {
        int v = (t >= off) ? part[t - off] : 0;
        __syncthreads();
        part[t] += v;
        __syncthreads();
    }
    int pre = (t == 0) ? 0 : part[t - 1];
#pragma unroll
    for (int i = 0; i < 16; ++i) {
        int idx = base + i;
        if (idx < NN) { rowptr[idx] = pre + loc[i]; cursor[idx] = pre + loc[i]; }
    }
    if (t == 1023) rowptr[NN] = part[1023];
}

__global__ __launch_bounds__(256) void k_place(const int* __restrict__ elist,
                                               int* __restrict__ cursor, int* __restrict__ epos) {
    int e = blockIdx.x * 256 + threadIdx.x;
    if (e < NE) {
        int n = elist[(size_t)e * 2 + 1];
        epos[e] = atomicAdd(&cursor[n], 1);
    }
}

// ---------------- kernel D: fused bilinear via MFMA (64 edges/block, 4 waves) ------------
// Identical to the round-3 proven kernel except output rows go to CSR slot epos[e].
#define HS 36
__global__ __launch_bounds__(256) void k_edge(
    const unsigned short* __restrict__ msgn_b,   // [NN][64]
    const unsigned short* __restrict__ hid_b,    // [NE][32]
    const int* __restrict__ elist, const float* __restrict__ eweight,
    const int* __restrict__ epos,
    const unsigned short* __restrict__ Wb,       // [33][64][64]
    const unsigned short* __restrict__ W0b,      // [64][32]
    const float* __restrict__ kb2,
    unsigned short* __restrict__ msg_out)        // [NE][64] bf16, CSR-permuted, *eweight
{
    __shared__ __align__(16) float hids[64 * HS];
    const int t = threadIdx.x;
    const int w = t >> 6, le = t & 15, g = (t >> 4) & 3;
    const int e0 = blockIdx.x * 64;

    for (int q = t; q < 512; q += 256) {
        int e = q >> 3, h4 = (q & 7) * 4;
        ushort4 hh = *(const ushort4*)(hid_b + (size_t)(e0 + e) * KHD + h4);
        float4 f; f.x = bf2f(hh.x); f.y = bf2f(hh.y); f.z = bf2f(hh.z); f.w = bf2f(hh.w);
        *(float4*)(hids + e * HS + h4) = f;
    }
    if (t < 64) hids[t * HS + 32] = 1.0f;

    int eid[4], ep[4];
#pragma unroll
    for (int nt = 0; nt < 4; ++nt) {
        eid[nt] = e0 + nt * 16 + le;
        ep[nt] = epos[eid[nt]];
    }

    bf16x8 bm[4][2];
#pragma unroll
    for (int nt = 0; nt < 4; ++nt) {
        int ni = elist[(size_t)eid[nt] * 2];
#pragma unroll
        for (int ks = 0; ks < 2; ++ks)
            bm[nt][ks] = *(const bf16x8*)(msgn_b + (size_t)ni * HD + ks * 32 + g * 8);
    }

    const f32x4 zz = {0.f, 0.f, 0.f, 0.f};
    f32x4 acc[4];
    {   // r=0 block: A[j][h]=kw2[h,j], B=hid (bf16), K=32
        bf16x8 a0 = *(const bf16x8*)(W0b + (w * 16 + le) * KHD + g * 8);
#pragma unroll
        for (int nt = 0; nt < 4; ++nt) {
            bf16x8 hb = *(const bf16x8*)(hid_b + (size_t)eid[nt] * KHD + g * 8);
            acc[nt] = __builtin_amdgcn_mfma_f32_16x16x32_bf16(a0, hb, zz, 0, 0, 0);
        }
    }
    __syncthreads();

#pragma unroll 3
    for (int h = 0; h < 33; ++h) {
        float hv[4];
#pragma unroll
        for (int nt = 0; nt < 4; ++nt) hv[nt] = hids[(nt * 16 + le) * HS + h];
        const unsigned short* wh = Wb + (size_t)h * 4096 + (w * 16 + le) * 64;
        bf16x8 a0 = *(const bf16x8*)(wh + g * 8);
        bf16x8 a1 = *(const bf16x8*)(wh + 32 + g * 8);
#pragma unroll
        for (int nt = 0; nt < 4; ++nt) {
            f32x4 c = __builtin_amdgcn_mfma_f32_16x16x32_bf16(a0, bm[nt][0], zz, 0, 0, 0);
            c = __builtin_amdgcn_mfma_f32_16x16x32_bf16(a1, bm[nt][1], c, 0, 0, 0);
            acc[nt] += hv[nt] * c;
        }
    }

    const int j = w * 16 + g * 4;
    float4 kbv = *(const float4*)(kb2 + j);
#pragma unroll
    for (int nt = 0; nt < 4; ++nt) {
        float ew = eweight[eid[nt]];
        ushort4 o;
        o.x = f2bf((acc[nt][0] + kbv.x) * ew);
        o.y = f2bf((acc[nt][1] + kbv.y) * ew);
        o.z = f2bf((acc[nt][2] + kbv.z) * ew);
        o.w = f2bf((acc[nt][3] + kbv.w) * ew);
        *(ushort4*)(msg_out + (size_t)ep[nt] * HD + j) = o;
    }
}

// ---------------- kernel E: streaming segment-sum + bn_upd/relu + MFMA GEMM + bn_out -----
#define UTS 72
__global__ __launch_bounds__(256) void k_out(
    const unsigned short* __restrict__ msg_out,  // CSR-ordered
    const int* __restrict__ rowptr,
    const unsigned short* __restrict__ w2b, const float* __restrict__ b2,
    const float* __restrict__ g_u, const float* __restrict__ be_u,
    const float* __restrict__ m_u, const float* __restrict__ v_u,
    const float* __restrict__ g_o, const float* __restrict__ be_o,
    const float* __restrict__ m_o, const float* __restrict__ v_o,
    float* __restrict__ out)
{
    __shared__ __align__(16) unsigned short utb[64 * UTS];
    __shared__ __align__(16) float sc_o[DOUT], sho2[DOUT], sc_u[HD], sh_u[HD];
    const int t = threadIdx.x;
    const int n0 = blockIdx.x * 64;
    {
        float s = g_o[t] * rsqrtf(v_o[t] + BN_EPS);
        sc_o[t] = s; sho2[t] = b2[t] * s + (be_o[t] - m_o[t] * s);
        if (t < HD) {
            float s2 = g_u[t] * rsqrtf(v_u[t] + BN_EPS);
            sc_u[t] = s2; sh_u[t] = be_u[t] - m_u[t] * s2;
        }
    }
    __syncthreads();
    {
        const int j = t & 63, qw = t >> 6;
        for (int r = qw; r < 64; r += 4) {
            int n = n0 + r;
            int p0 = rowptr[n], p1 = rowptr[n + 1];
            float a = 0.f;
            for (int p = p0; p < p1; ++p)
                a += bf2f(msg_out[(size_t)p * HD + j]);
            utb[r * UTS + j] = f2bf(fmaxf(fmaf(a, sc_u[j], sh_u[j]), 0.f));
        }
    }
    __syncthreads();
    const int w = t >> 6, le = t & 15, g = (t >> 4) & 3;
    const f32x4 zz = {0.f, 0.f, 0.f, 0.f};
    f32x4 acc[4][4];
#pragma unroll
    for (int jt = 0; jt < 4; ++jt)
#pragma unroll
        for (int nt = 0; nt < 4; ++nt) acc[jt][nt] = zz;
#pragma unroll
    for (int ks = 0; ks < 2; ++ks) {
        bf16x8 b[4];
#pragma unroll
        for (int nt = 0; nt < 4; ++nt)
            b[nt] = *(const bf16x8*)(utb + (nt * 16 + le) * UTS + ks * 32 + g * 8);
#pragma unroll
        for (int jt = 0; jt < 4; ++jt) {
            bf16x8 a = *(const bf16x8*)(w2b + (size_t)(w * 64 + jt * 16 + le) * HD + ks * 32 + g * 8);
#pragma unroll
            for (int nt = 0; nt < 4; ++nt)
                acc[jt][nt] = __builtin_amdgcn_mfma_f32_16x16x32_bf16(a, b[nt], acc[jt][nt], 0, 0, 0);
        }
    }
#pragma unroll
    for (int jt = 0; jt < 4; ++jt) {
        int c = w * 64 + jt * 16 + g * 4;
        float4 sc = *(const float4*)(sc_o + c);
        float4 sh = *(const float4*)(sho2 + c);
#pragma unroll
        for (int nt = 0; nt < 4; ++nt) {
            int n = n0 + nt * 16 + le;
            float4 o;
            o.x = fmaf(acc[jt][nt][0], sc.x, sh.x);
            o.y = fmaf(acc[jt][nt][1], sc.y, sh.y);
            o.z = fmaf(acc[jt][nt][2], sc.z, sh.z);
            o.w = fmaf(acc[jt][nt][3], sc.w, sh.w);
            *(float4*)(out + (size_t)n * DOUT + c) = o;
        }
    }
}

extern "C" void kernel_launch(void* const* d_in, const int* in_sizes, int n_in,
                              void* d_out, int out_size, void* d_ws, size_t ws_size,
                              hipStream_t stream)
{
    (void)in_sizes; (void)n_in; (void)out_size; (void)ws_size;
    const float* x    = (const float*)d_in[0];
    const float* ei   = (const float*)d_in[1];
    const int*   el   = (const int*)  d_in[2];
    const float* ew   = (const float*)d_in[3];
    const float* w1   = (const float*)d_in[4];
    const float* b1   = (const float*)d_in[5];
    const float* kw1  = (const float*)d_in[6];
    const float* kb1  = (const float*)d_in[7];
    const float* kw2  = (const float*)d_in[8];
    const float* kb2  = (const float*)d_in[9];
    const float* w2   = (const float*)d_in[10];
    const float* b2   = (const float*)d_in[11];
    const float* g_in = (const float*)d_in[12], *be_in = (const float*)d_in[13];
    const float* m_in = (const float*)d_in[14], *v_in  = (const float*)d_in[15];
    const float* g_m  = (const float*)d_in[16], *be_m  = (const float*)d_in[17];
    const float* m_m  = (const float*)d_in[18], *v_m   = (const float*)d_in[19];
    const float* g_u  = (const float*)d_in[20], *be_u  = (const float*)d_in[21];
    const float* m_u  = (const float*)d_in[22], *v_u   = (const float*)d_in[23];
    const float* g_o  = (const float*)d_in[24], *be_o  = (const float*)d_in[25];
    const float* m_o  = (const float*)d_in[26], *v_o   = (const float*)d_in[27];

    char* wsb = (char*)d_ws;
    size_t off = 0;
    auto alloc = [&](size_t bytes) -> void* {
        void* p = wsb + off; off += (bytes + 255) & ~(size_t)255; return p;
    };
    unsigned short* msgn_b  = (unsigned short*)alloc((size_t)NN * HD * 2);
    unsigned short* hid_b   = (unsigned short*)alloc((size_t)NE * KHD * 2);
    unsigned short* Wb      = (unsigned short*)alloc((size_t)33 * 4096 * 2);
    unsigned short* W0b     = (unsigned short*)alloc((size_t)64 * KHD * 2);
    unsigned short* w1b     = (unsigned short*)alloc((size_t)HD * DIN * 2);
    unsigned short* kw1b    = (unsigned short*)alloc((size_t)KHD * DE * 2);
    unsigned short* w2b     = (unsigned short*)alloc((size_t)DOUT * HD * 2);
    int* rowptr = (int*)alloc((size_t)(NN + 1) * 4);
    int* epos   = (int*)alloc((size_t)NE * 4);
    // union: deg+cursor live only until k_place; msg_out written after (k_edge)
    char* un = (char*)alloc((size_t)NE * HD * 2);
    unsigned short* msg_out = (unsigned short*)un;
    int* deg    = (int*)un;
    int* cursor = (int*)(un + (((size_t)NN * 4 + 255) & ~(size_t)255));

    hipMemsetAsync(deg, 0, (size_t)NN * 4, stream);
    hipLaunchKernelGGL(k_prep, dim3(680), dim3(256), 0, stream,
                       kw2, kb2, w1, kw1, w2, Wb, W0b, w1b, kw1b, w2b);
    hipLaunchKernelGGL(k_deg, dim3(NE / 256), dim3(256), 0, stream, el, deg);
    hipLaunchKernelGGL(k_scan, dim3(1), dim3(1024), 0, stream, deg, rowptr, cursor);
    hipLaunchKernelGGL(k_place, dim3(NE / 256), dim3(256), 0, stream, el, cursor, epos);
    hipLaunchKernelGGL(k_msgn, dim3(NN / 64), dim3(256), 0, stream,
                       x, w1b, b1, g_in, be_in, m_in, v_in, g_m, be_m, m_m, v_m, msgn_b);
    hipLaunchKernelGGL(k_hidden, dim3(NE / 64), dim3(256), 0, stream,
                       ei, kw1b, kb1, hid_b);
    hipLaunchKernelGGL(k_edge, dim3(NE / 64), dim3(256), 0, stream,
                       msgn_b, hid_b, el, ew, epos, Wb, W0b, kb2, msg_out);
    hipLaunchKernelGGL(k_out, dim3(NN / 64), dim3(256), 0, stream,
                       msg_out, rowptr, w2b, b2, g_u, be_u, m_u, v_u,
                       g_o, be_o, m_o, v_o, (float*)d_out);
}